// Round 2
// baseline (4807.380 us; speedup 1.0000x reference)
//
#include <hip/hip_runtime.h>
#include <hip/hip_bf16.h>

#define B_  512
#define T_  256
#define E_  256
#define H_  512
#define V_  1000
#define CH  16   // chunk of timesteps buffered before deferred output projection

typedef __attribute__((ext_vector_type(8))) short short8;
typedef __attribute__((ext_vector_type(4))) float f32x4;
typedef __hip_bfloat16 bf16;

#define MFMA16(a, b, c) __builtin_amdgcn_mfma_f32_16x16x32_bf16((a), (b), (c), 0, 0, 0)

// ---------------------------------------------------------------------------
// fp32 -> bf16 pre-conversion (weights/embedding), 8 elems/thread
// ---------------------------------------------------------------------------
__global__ void f32_to_bf16_kernel(const float* __restrict__ src,
                                   bf16* __restrict__ dst, int n8) {
  int i = blockIdx.x * blockDim.x + threadIdx.x;
  if (i >= n8) return;
  const float4* s4 = (const float4*)src;
  float4 a = s4[2 * i], b = s4[2 * i + 1];
  bf16 tmp[8] = {__float2bfloat16(a.x), __float2bfloat16(a.y),
                 __float2bfloat16(a.z), __float2bfloat16(a.w),
                 __float2bfloat16(b.x), __float2bfloat16(b.y),
                 __float2bfloat16(b.z), __float2bfloat16(b.w)};
  *(int4*)(dst + 8 * i) = *(const int4*)tmp;
}

// ---------------------------------------------------------------------------
// Per-step gates + LSTM cell kernel (layer 1 only; layer 0 is dead code:
// both cells take x_t and the output depends only on h1).
// grid (8, 32): x -> 64-row batch block, y -> 16-wide hidden-column block.
// Block computes gate cols {g*512 + j0..j0+15, g=0..3} so each lane ends up
// holding matching i,f,g,o values -> fused cell update, no shuffles.
// ---------------------------------------------------------------------------
__global__ __launch_bounds__(256) void gates_cell_kernel(
    const bf16* __restrict__ emb, const int* __restrict__ gt,
    const bf16* __restrict__ W_ih, const bf16* __restrict__ W_hh,
    const float* __restrict__ b_ih, const float* __restrict__ b_hh,
    const bf16* __restrict__ h_prev, float* __restrict__ c_state,
    bf16* __restrict__ h_out, int t)
{
  __shared__ short As[64][40];   // +8 pad: 2-way bank aliasing only (free)
  __shared__ short Bs[64][40];
  __shared__ int chars[64];

  const int tid  = threadIdx.x;
  const int wave = tid >> 6, lane = tid & 63;
  const int m0 = blockIdx.x * 64;
  const int j0 = blockIdx.y * 16;

  if (tid < 64) {
    int m = m0 + tid;
    chars[tid] = (t == 0) ? 0 : gt[m * T_ + (t - 1)];  // EOS_IDX = 0
  }
  __syncthreads();

  // staging: 256 threads cover 64 rows x 32 k (16B each)
  const int sr  = tid >> 2;          // tile row 0..63
  const int skc = (tid & 3) * 8;     // k offset in elements
  const int sg  = sr >> 4, sjj = sr & 15;
  const int wr  = sg * H_ + j0 + sjj;  // weight (gate) row for B staging

  const int q   = lane >> 4, col = lane & 15;
  const int mr  = wave * 16 + col;   // a-frag LDS row for this lane
  const int ko  = q * 8;             // frag k offset within 32-wide K tile

  f32x4 acc0 = {0.f,0.f,0.f,0.f}, acc1 = acc0, acc2 = acc0, acc3 = acc0;

  // ---- phase A: x_t @ W_ih^T  (K = 256, A rows gathered from embedding)
  for (int k0 = 0; k0 < E_; k0 += 32) {
    const short* asrc = (const short*)emb + (size_t)chars[sr] * E_ + k0 + skc;
    const short* bsrc = (const short*)W_ih + (size_t)wr * E_ + k0 + skc;
    *(int4*)&As[sr][skc] = *(const int4*)asrc;
    *(int4*)&Bs[sr][skc] = *(const int4*)bsrc;
    __syncthreads();
    short8 a  = *(const short8*)&As[mr][ko];
    short8 b0 = *(const short8*)&Bs[ 0 + col][ko];
    short8 b1 = *(const short8*)&Bs[16 + col][ko];
    short8 b2 = *(const short8*)&Bs[32 + col][ko];
    short8 b3 = *(const short8*)&Bs[48 + col][ko];
    acc0 = MFMA16(a, b0, acc0);
    acc1 = MFMA16(a, b1, acc1);
    acc2 = MFMA16(a, b2, acc2);
    acc3 = MFMA16(a, b3, acc3);
    __syncthreads();
  }
  // ---- phase B: h_prev @ W_hh^T  (K = 512)
  for (int k0 = 0; k0 < H_; k0 += 32) {
    const short* asrc = (const short*)h_prev + (size_t)(m0 + sr) * H_ + k0 + skc;
    const short* bsrc = (const short*)W_hh + (size_t)wr * H_ + k0 + skc;
    *(int4*)&As[sr][skc] = *(const int4*)asrc;
    *(int4*)&Bs[sr][skc] = *(const int4*)bsrc;
    __syncthreads();
    short8 a  = *(const short8*)&As[mr][ko];
    short8 b0 = *(const short8*)&Bs[ 0 + col][ko];
    short8 b1 = *(const short8*)&Bs[16 + col][ko];
    short8 b2 = *(const short8*)&Bs[32 + col][ko];
    short8 b3 = *(const short8*)&Bs[48 + col][ko];
    acc0 = MFMA16(a, b0, acc0);
    acc1 = MFMA16(a, b1, acc1);
    acc2 = MFMA16(a, b2, acc2);
    acc3 = MFMA16(a, b3, acc3);
    __syncthreads();
  }

  // ---- fused LSTM cell update (gate order i, f, g, o)
  const int j = j0 + col;
  float bi0 = b_ih[0 * H_ + j] + b_hh[0 * H_ + j];
  float bi1 = b_ih[1 * H_ + j] + b_hh[1 * H_ + j];
  float bi2 = b_ih[2 * H_ + j] + b_hh[2 * H_ + j];
  float bi3 = b_ih[3 * H_ + j] + b_hh[3 * H_ + j];
#pragma unroll
  for (int r = 0; r < 4; r++) {
    int m = m0 + wave * 16 + q * 4 + r;   // C/D layout: row = quad*4 + reg
    float iv = 1.f / (1.f + __expf(-(acc0[r] + bi0)));
    float fv = 1.f / (1.f + __expf(-(acc1[r] + bi1)));
    float gv = tanhf(acc2[r] + bi2);
    float ov = 1.f / (1.f + __expf(-(acc3[r] + bi3)));
    float cOld = c_state[(size_t)m * H_ + j];
    float cN = fv * cOld + iv * gv;
    c_state[(size_t)m * H_ + j] = cN;
    h_out[(size_t)m * H_ + j] = __float2bfloat16(ov * tanhf(cN));
  }
}

// ---------------------------------------------------------------------------
// Deferred output projection + log_softmax over a CH-step chunk of h1.
// grid 16*CH: blockIdx >> 4 = step-in-chunk, (blockIdx & 15)*32 = batch base.
// Block computes logits[32 rows][1000 cols] in fp32 registers (K=512 MFMA),
// then fused log-softmax via quad-shuffles + small LDS cross-wave reduce.
// ---------------------------------------------------------------------------
__global__ __launch_bounds__(256) void out_proj_kernel(
    const bf16* __restrict__ h1buf,   // [CH][B][H]
    const bf16* __restrict__ Wout,    // [V][H] bf16 (pre-converted)
    const float* __restrict__ bout,   // [V] fp32
    float* __restrict__ out,          // [B][T][V] fp32
    int t0)
{
  __shared__ short Hs[32][520];       // 32 rows x 512 k, +8 pad
  __shared__ float red[4][32];
  __shared__ float rowM[32];
  __shared__ float rowS[32];

  const int tid  = threadIdx.x;
  const int wave = tid >> 6, lane = tid & 63;
  const int q = lane >> 4, col = lane & 15;
  const int s  = blockIdx.x >> 4;          // step within chunk
  const int b0 = (blockIdx.x & 15) * 32;   // batch base

  const short* hrow = (const short*)h1buf + ((size_t)s * B_ + b0) * H_;
  for (int c = tid; c < 2048; c += 256) {
    int r = c >> 6, kc = (c & 63) << 3;
    *(int4*)&Hs[r][kc] = *(const int4*)&hrow[r * H_ + kc];
  }
  __syncthreads();

  f32x4 acc[2][16];
#pragma unroll
  for (int mt = 0; mt < 2; mt++)
#pragma unroll
    for (int u = 0; u < 16; u++) acc[mt][u] = (f32x4){0.f, 0.f, 0.f, 0.f};

  const short* WS = (const short*)Wout;
  for (int k0 = 0; k0 < H_; k0 += 32) {
    short8 a0 = *(const short8*)&Hs[col][k0 + q * 8];
    short8 a1 = *(const short8*)&Hs[16 + col][k0 + q * 8];
#pragma unroll
    for (int u = 0; u < 16; u++) {
      int nt = wave + 4 * u;             // n-tile index, 63 tiles total
      if (nt < 63) {
        int v = nt * 16 + col;
        int vc = v < V_ ? v : (V_ - 1);  // clamp OOB rows of W_out
        short8 bfr = *(const short8*)&WS[(size_t)vc * H_ + k0 + q * 8];
        acc[0][u] = MFMA16(a0, bfr, acc[0][u]);
        acc[1][u] = MFMA16(a1, bfr, acc[1][u]);
      }
    }
  }

  // ---- fused log_softmax; logits stay in regs
  float bo[16];
  bool  val[16];
#pragma unroll
  for (int u = 0; u < 16; u++) {
    int nt = wave + 4 * u;
    int v = nt * 16 + col;
    val[u] = (nt < 63) && (v < V_);
    bo[u] = val[u] ? bout[v] : 0.f;
  }

  float mymax[2][4];
#pragma unroll
  for (int mt = 0; mt < 2; mt++)
#pragma unroll
    for (int r = 0; r < 4; r++) mymax[mt][r] = -1e30f;
#pragma unroll
  for (int mt = 0; mt < 2; mt++)
#pragma unroll
    for (int u = 0; u < 16; u++)
      if (val[u]) {
#pragma unroll
        for (int r = 0; r < 4; r++)
          mymax[mt][r] = fmaxf(mymax[mt][r], acc[mt][u][r] + bo[u]);
      }
#pragma unroll
  for (int d = 1; d < 16; d <<= 1)
#pragma unroll
    for (int mt = 0; mt < 2; mt++)
#pragma unroll
      for (int r = 0; r < 4; r++)
        mymax[mt][r] = fmaxf(mymax[mt][r], __shfl_xor(mymax[mt][r], d, 64));
  if (col == 0)
#pragma unroll
    for (int mt = 0; mt < 2; mt++)
#pragma unroll
      for (int r = 0; r < 4; r++)
        red[wave][mt * 16 + q * 4 + r] = mymax[mt][r];
  __syncthreads();
  if (tid < 32)
    rowM[tid] = fmaxf(fmaxf(red[0][tid], red[1][tid]),
                      fmaxf(red[2][tid], red[3][tid]));
  __syncthreads();

  float mysum[2][4] = {{0.f,0.f,0.f,0.f},{0.f,0.f,0.f,0.f}};
#pragma unroll
  for (int mt = 0; mt < 2; mt++)
#pragma unroll
    for (int r = 0; r < 4; r++) {
      float rm = rowM[mt * 16 + q * 4 + r];
#pragma unroll
      for (int u = 0; u < 16; u++)
        if (val[u]) mysum[mt][r] += __expf(acc[mt][u][r] + bo[u] - rm);
    }
#pragma unroll
  for (int d = 1; d < 16; d <<= 1)
#pragma unroll
    for (int mt = 0; mt < 2; mt++)
#pragma unroll
      for (int r = 0; r < 4; r++)
        mysum[mt][r] += __shfl_xor(mysum[mt][r], d, 64);
  if (col == 0)
#pragma unroll
    for (int mt = 0; mt < 2; mt++)
#pragma unroll
      for (int r = 0; r < 4; r++)
        red[wave][mt * 16 + q * 4 + r] = mysum[mt][r];
  __syncthreads();
  if (tid < 32)
    rowS[tid] = __logf(red[0][tid] + red[1][tid] + red[2][tid] + red[3][tid]);
  __syncthreads();

#pragma unroll
  for (int mt = 0; mt < 2; mt++)
#pragma unroll
    for (int r = 0; r < 4; r++) {
      int m = mt * 16 + q * 4 + r;
      float corr = rowM[m] + rowS[m];
      size_t base = ((size_t)(b0 + m) * T_ + (t0 + s)) * V_;
#pragma unroll
      for (int u = 0; u < 16; u++)
        if (val[u]) {
          int v = (wave + 4 * u) * 16 + col;
          out[base + v] = acc[mt][u][r] + bo[u] - corr;
        }
    }
}

// ---------------------------------------------------------------------------
extern "C" void kernel_launch(void* const* d_in, const int* in_sizes, int n_in,
                              void* d_out, int out_size, void* d_ws, size_t ws_size,
                              hipStream_t stream) {
  (void)in_sizes; (void)n_in; (void)out_size; (void)ws_size;
  const int*   gt     = (const int*)d_in[1];
  const float* emb_f  = (const float*)d_in[2];
  // layer 0 weights d_in[3..6] dead code; listener_output d_in[0] unused by ref
  const float* Wih_f  = (const float*)d_in[7];
  const float* Whh_f  = (const float*)d_in[8];
  const float* b_ih1  = (const float*)d_in[9];
  const float* b_hh1  = (const float*)d_in[10];
  const float* Wout_f = (const float*)d_in[11];
  const float* bout   = (const float*)d_in[12];
  float* out = (float*)d_out;

  // ws layout (16B-aligned sections):
  //   c_state f32 [B][H]           1,048,576 B @ 0
  //   hinit   bf16 [B][H] zeros      524,288 B @ 1,048,576
  //   h1buf   bf16 [CH][B][H]      8,388,608 B @ 1,572,864
  //   emb_bf  bf16 [V][E]            512,000 B @ 9,961,472
  //   Wih_bf  bf16 [2048][256]     1,048,576 B @ 10,473,472
  //   Whh_bf  bf16 [2048][512]     2,097,152 B @ 11,522,048
  //   Wout_bf bf16 [1000][512]     1,024,000 B @ 13,619,200   (total ~14.6 MB)
  char* ws = (char*)d_ws;
  float* c_state = (float*)ws;
  bf16*  hinit   = (bf16*)(ws + 1048576);
  bf16*  h1buf   = (bf16*)(ws + 1572864);
  bf16*  emb_bf  = (bf16*)(ws + 9961472);
  bf16*  Wih_bf  = (bf16*)(ws + 10473472);
  bf16*  Whh_bf  = (bf16*)(ws + 11522048);
  bf16*  Wout_bf = (bf16*)(ws + 13619200);

  hipMemsetAsync(d_ws, 0, 1572864, stream);  // zero c_state + hinit

  // pre-convert fp32 weights/embedding to bf16
  f32_to_bf16_kernel<<<(V_ * E_ / 8 + 255) / 256, 256, 0, stream>>>(emb_f, emb_bf, V_ * E_ / 8);
  f32_to_bf16_kernel<<<(4 * H_ * E_ / 8 + 255) / 256, 256, 0, stream>>>(Wih_f, Wih_bf, 4 * H_ * E_ / 8);
  f32_to_bf16_kernel<<<(4 * H_ * H_ / 8 + 255) / 256, 256, 0, stream>>>(Whh_f, Whh_bf, 4 * H_ * H_ / 8);
  f32_to_bf16_kernel<<<(V_ * H_ / 8 + 255) / 256, 256, 0, stream>>>(Wout_f, Wout_bf, V_ * H_ / 8);

  for (int t = 0; t < T_; t++) {
    const bf16* hp = (t == 0) ? hinit
                              : h1buf + (size_t)((t - 1) & (CH - 1)) * B_ * H_;
    bf16* ho = h1buf + (size_t)(t & (CH - 1)) * B_ * H_;
    gates_cell_kernel<<<dim3(8, 32), 256, 0, stream>>>(
        emb_bf, gt, Wih_bf, Whh_bf, b_ih1, b_hh1, hp, c_state, ho, t);
    if ((t & (CH - 1)) == (CH - 1)) {
      out_proj_kernel<<<16 * CH, 256, 0, stream>>>(h1buf, Wout_bf, bout, out,
                                                   t - (CH - 1));
    }
  }
}